// Round 13
// baseline (287.598 us; speedup 1.0000x reference)
//
#include <hip/hip_runtime.h>
#include <hip/hip_fp16.h>
#include <math.h>
#include <stdint.h>

#define EPB 4096          // edges per block in partition kernels
#define NBKT 128          // dst>>9 buckets (98 used for N=50000)

typedef _Float16 f16x8 __attribute__((ext_vector_type(8)));
typedef float f32x4 __attribute__((ext_vector_type(4)));
typedef float f32x2 __attribute__((ext_vector_type(2)));
typedef _Float16 h2 __attribute__((ext_vector_type(2)));

#define LOG2E 1.4426950f

__device__ __forceinline__ float fast_exp2(float x) {
#if __has_builtin(__builtin_amdgcn_exp2f)
    return __builtin_amdgcn_exp2f(x);
#else
    return __expf(x * 0.69314718f);
#endif
}

// ---------- 16-lane row sum via DPP (builtin: compiler handles hazards) ----
template<int CTRL>
__device__ __forceinline__ float dpp_add(float x) {
    union { float f; int i; } u, v;
    u.f = x;
    v.i = __builtin_amdgcn_update_dpp(0, u.i, CTRL, 0xF, 0xF, true);
    return x + v.f;
}
__device__ __forceinline__ float reduce16(float x) {
    x = dpp_add<0xB1>(x);   // quad_perm xor1
    x = dpp_add<0x4E>(x);   // quad_perm xor2
    x = dpp_add<0x124>(x);  // row_ror:4
    x = dpp_add<0x128>(x);  // row_ror:8
    return x;               // all 16 lanes of the row hold the row sum
}

// ---------- pack both layers' W into MFMA B-frag order (one launch) --------
// Layer1: K=K1, no perm -> Wp1.  Layer2: K=128, paired-K perm -> Wp2.
__global__ void k_wpack_all(const float* __restrict__ Wl1, const float* __restrict__ Wr1,
                            const float* __restrict__ Wl2, const float* __restrict__ Wr2,
                            _Float16* __restrict__ Wp1, _Float16* __restrict__ Wp2,
                            int K1) {
    int t = blockIdx.x * 256 + threadIdx.x;
    int total1 = (K1 / 32) * 16 * 64;
    int total2 = (128 / 32) * 16 * 64;
    if (t < total1) {
        int l = t & 63, ct = (t >> 6) & 15, kt = t >> 10;
        int col = ct * 16 + (l & 15);
        int k0 = kt * 32 + (l >> 4) * 8;
        const float* src = (col < 128) ? (Wl1 + (size_t)col * K1)
                                       : (Wr1 + (size_t)(col - 128) * K1);
        union { _Float16 h[8]; uint4 u; } o;
#pragma unroll
        for (int e = 0; e < 8; ++e) o.h[e] = (_Float16)src[k0 + e];
        reinterpret_cast<uint4*>(Wp1)[t] = o.u;
    } else if (t < total1 + total2) {
        int t2 = t - total1;
        int l = t2 & 63, ct = (t2 >> 6) & 15, kt = t2 >> 10;
        int col = ct * 16 + (l & 15);
        int k0 = kt * 32 + (l >> 4) * 8;
        const float* src = (col < 128) ? (Wl2 + (size_t)col * 128)
                                       : (Wr2 + (size_t)(col - 128) * 128);
        union { _Float16 h[8]; uint4 u; } o;
#pragma unroll
        for (int e = 0; e < 8; ++e) {
            int k = k0 + e;
            int m = k >> 1, hh = m >> 4, j = m & 15;
            int c0 = hh * 32 + j;
            int chan = (k & 1) ? c0 + 16 : c0;
            o.h[e] = (_Float16)src[chan];
        }
        reinterpret_cast<uint4*>(Wp2)[t2] = o.u;
    }
}

// ---------- MFMA GEMM (BM=64) with fused prep epilogue ----------
// Waves 0,1 own xl cols: bias, fp16 PAIRS to xlh, ledl = 0.6*log2e*(att.xl).
// Waves 2,3 own xr cols: bias, paired float2 to xrp.
template<int K, int CVT>
__global__ __launch_bounds__(256) void k_gemm_mfma(
    const void* __restrict__ Xin, const _Float16* __restrict__ Wp,
    const float* __restrict__ bl, const float* __restrict__ br,
    const float* __restrict__ att,
    uint32_t* __restrict__ xlh, float2* __restrict__ xrp,
    float* __restrict__ ledl, int N) {
    __shared__ _Float16 xs[64 * K];
    const int t = threadIdx.x, w = t >> 6, l = t & 63;
    const int row0 = blockIdx.x * 64;
    if (CVT) {
        const float* X = (const float*)Xin;
        for (int cid = t; cid < 64 * (K / 4); cid += 256) {
            int r = cid / (K / 4), c4 = (cid % (K / 4)) * 4;
            int gr = row0 + r;
            float4 v = make_float4(0.f, 0.f, 0.f, 0.f);
            if (gr < N) v = *reinterpret_cast<const float4*>(X + (size_t)gr * K + c4);
            h2 lo = {(_Float16)v.x, (_Float16)v.y};
            h2 hi = {(_Float16)v.z, (_Float16)v.w};
            uint2 pk;
            pk.x = __builtin_bit_cast(uint32_t, lo);
            pk.y = __builtin_bit_cast(uint32_t, hi);
            int ba = (r * K * 2 + c4 * 2) ^ ((r & 7) << 4);
            *reinterpret_cast<uint2*>(reinterpret_cast<char*>(xs) + ba) = pk;
        }
    } else {
        const _Float16* X = (const _Float16*)Xin;
        for (int cid = t; cid < 64 * (K / 8); cid += 256) {
            int r = cid / (K / 8), c8 = (cid % (K / 8)) * 8;
            int gr = row0 + r;
            uint4 v = make_uint4(0u, 0u, 0u, 0u);
            if (gr < N) v = *reinterpret_cast<const uint4*>(X + (size_t)gr * K + c8);
            int ba = (r * K * 2 + c8 * 2) ^ ((r & 7) << 4);
            *reinterpret_cast<uint4*>(reinterpret_cast<char*>(xs) + ba) = v;
        }
    }
    __syncthreads();
    f32x4 acc[4][4];
#pragma unroll
    for (int m = 0; m < 4; ++m)
#pragma unroll
        for (int n = 0; n < 4; ++n) acc[m][n] = (f32x4){0.f, 0.f, 0.f, 0.f};
#pragma unroll
    for (int kt = 0; kt < K / 32; ++kt) {
        f16x8 a[4], b[4];
#pragma unroll
        for (int m = 0; m < 4; ++m) {
            int r = m * 16 + (l & 15);
            int ba = (r * K * 2 + kt * 64 + (l >> 4) * 16) ^ ((r & 7) << 4);
            a[m] = *reinterpret_cast<const f16x8*>(reinterpret_cast<const char*>(xs) + ba);
        }
#pragma unroll
        for (int n = 0; n < 4; ++n) {
            int ct = w * 4 + n;
            b[n] = *reinterpret_cast<const f16x8*>(Wp + ((size_t)(kt * 16 + ct) * 64 + l) * 8);
        }
#pragma unroll
        for (int m = 0; m < 4; ++m)
#pragma unroll
            for (int n = 0; n < 4; ++n)
                acc[m][n] = __builtin_amdgcn_mfma_f32_16x16x32_f16(a[m], b[n], acc[m][n], 0, 0, 0);
    }
    const int j = l & 15;
    if (w < 2) {
        float attv[2][2], bv[2][2];
#pragma unroll
        for (int p = 0; p < 2; ++p) {
            int c0 = (2 * w + p) * 32 + j;
            attv[p][0] = att[c0]; attv[p][1] = att[c0 + 16];
            bv[p][0] = bl[c0];    bv[p][1] = bl[c0 + 16];
        }
#pragma unroll
        for (int m = 0; m < 4; ++m)
#pragma unroll
            for (int r4 = 0; r4 < 4; ++r4) {
                int gr = row0 + m * 16 + (l >> 4) * 4 + r4;
                bool ok = gr < N;
#pragma unroll
                for (int p = 0; p < 2; ++p) {
                    int h = 2 * w + p;
                    float v0 = acc[m][2 * p][r4] + bv[p][0];
                    float v1 = acc[m][2 * p + 1][r4] + bv[p][1];
                    float part = reduce16(fmaf(attv[p][0], v0, attv[p][1] * v1));
                    if (ok) {
                        h2 hp = {(_Float16)v0, (_Float16)v1};
                        xlh[(size_t)gr * 64 + h * 16 + j] = __builtin_bit_cast(uint32_t, hp);
                        if (j == 0) ledl[gr * 4 + h] = 0.6f * LOG2E * part;
                    }
                }
            }
    } else {
        float bv[2][2];
#pragma unroll
        for (int p = 0; p < 2; ++p) {
            int c0 = (2 * (w - 2) + p) * 32 + j;
            bv[p][0] = br[c0]; bv[p][1] = br[c0 + 16];
        }
#pragma unroll
        for (int m = 0; m < 4; ++m)
#pragma unroll
            for (int r4 = 0; r4 < 4; ++r4) {
                int gr = row0 + m * 16 + (l >> 4) * 4 + r4;
                if (gr < N) {
#pragma unroll
                    for (int p = 0; p < 2; ++p) {
                        int hh = 2 * (w - 2) + p;
                        float v0 = acc[m][2 * p][r4] + bv[p][0];
                        float v1 = acc[m][2 * p + 1][r4] + bv[p][1];
                        xrp[(size_t)gr * 64 + hh * 16 + j] = make_float2(v0, v1);
                    }
                }
            }
    }
}

// ---------------- radix partition by dst>>9 (scan-based, no global RMW) ----
// Also zeroes the pool buffer (folded launch).
__global__ __launch_bounds__(256) void k_hist(const int* __restrict__ dstArr,
                                              int* __restrict__ g_hist, int E,
                                              float* __restrict__ zbuf, int zn) {
    __shared__ int h[NBKT];
    int t = threadIdx.x;
    int zi = blockIdx.x * 256 + t;
    if (zi < zn) zbuf[zi] = 0.f;
    if (t < NBKT) h[t] = 0;
    __syncthreads();
    int s0 = blockIdx.x * EPB, s1 = min(E, s0 + EPB);
    for (int i = s0 + t; i < s1; i += 256) atomicAdd(&h[dstArr[i] >> 9], 1);
    __syncthreads();
    if (t < NBKT) g_hist[blockIdx.x * NBKT + t] = h[t];
}
__global__ __launch_bounds__(512) void k_part_scan(const int* __restrict__ g_hist,
                                                   int* __restrict__ g_base,
                                                   int* __restrict__ bstart_out,
                                                   int NB1, int E) {
    __shared__ int csum[4][NBKT];
    __shared__ int btot[NBKT];
    __shared__ int bstart[NBKT];
    int tid = threadIdx.x, c = tid >> 7, b = tid & (NBKT - 1);
    int chunk = (NB1 + 3) >> 2;
    int i0 = c * chunk, i1 = min(NB1, i0 + chunk);
    int run = 0;
    for (int i = i0; i < i1; ++i) run += g_hist[i * NBKT + b];
    csum[c][b] = run;
    __syncthreads();
    int mytot = 0;
    if (c == 0) {
        mytot = csum[0][b] + csum[1][b] + csum[2][b] + csum[3][b];
        btot[b] = mytot;
    }
    __syncthreads();
    for (int off = 1; off < NBKT; off <<= 1) {
        int add = 0;
        if (c == 0 && b >= off) add = btot[b - off];
        __syncthreads();
        if (c == 0) btot[b] += add;
        __syncthreads();
    }
    if (c == 0) { bstart[b] = btot[b] - mytot; bstart_out[b] = bstart[b]; }
    if (tid == 0) bstart_out[NBKT] = E;
    __syncthreads();
    int base = bstart[b];
    for (int cc = 0; cc < c; ++cc) base += csum[cc][b];
    run = base;
    for (int i = i0; i < i1; ++i) {
        g_base[i * NBKT + b] = run;
        run += g_hist[i * NBKT + b];
    }
}
__global__ __launch_bounds__(256) void k_scatter(const int* __restrict__ ei,
                                                 const int* __restrict__ g_base,
                                                 uint32_t* __restrict__ tmp, int E) {
    __shared__ int off[NBKT];
    int t = threadIdx.x;
    if (t < NBKT) off[t] = g_base[blockIdx.x * NBKT + t];
    __syncthreads();
    int s0 = blockIdx.x * EPB, s1 = min(E, s0 + EPB);
    for (int i = s0 + t; i < s1; i += 256) {
        int s = ei[i], d = ei[E + i];
        int pos = atomicAdd(&off[d >> 9], 1);
        tmp[pos] = ((uint32_t)s << 16) | (uint32_t)d;
    }
}
// One block per 512-node bucket: LDS hist+scan -> rowptr, self-loops, and
// ordered edge placement, all within a ~67KB contiguous csr window.
__global__ __launch_bounds__(256) void k_bucket_csr(
    const uint32_t* __restrict__ tmp, const int* __restrict__ bstart,
    int* __restrict__ rowptr, int* __restrict__ csr, int N, int E) {
    __shared__ int cnt[512];
    __shared__ int fil[512];
    int b = blockIdx.x, t = threadIdx.x;
    int s0 = bstart[b], s1 = bstart[b + 1];
    cnt[t] = 0; cnt[t + 256] = 0;
    __syncthreads();
    for (int i = s0 + t; i < s1; i += 256)
        atomicAdd(&cnt[tmp[i] & 511], 1);
    __syncthreads();
    int c0 = cnt[t], c1 = cnt[t + 256];
    for (int off = 1; off < 512; off <<= 1) {
        int v0 = (t >= off) ? cnt[t - off] : 0;
        int v1 = (t + 256 >= off) ? cnt[t + 256 - off] : 0;
        __syncthreads();
        cnt[t] += v0; cnt[t + 256] += v1;
        __syncthreads();
    }
    int e0 = cnt[t] - c0, e1 = cnt[t + 256] - c1;   // exclusive
    __syncthreads();
    cnt[t] = e0; cnt[t + 256] = e1;
    fil[t] = 1; fil[t + 256] = 1;                   // slot 0 = self-loop
    __syncthreads();
    int n0 = b * 512;
#pragma unroll
    for (int k = 0; k < 2; ++k) {
        int ld = t + k * 256, n = n0 + ld;
        if (n < N) {
            int rp = s0 + cnt[ld] + n;              // edgesBefore + selfLoopsBefore
            rowptr[n] = rp;
            csr[rp] = n;
        }
    }
    if (b == 0 && t == 0) rowptr[N] = E + N;
    for (int i = s0 + t; i < s1; i += 256) {
        uint32_t pk = tmp[i];
        int d = (int)(pk & 0xFFFFu), ld = d & 511;
        int slot = atomicAdd(&fil[ld], 1);
        csr[s0 + cnt[ld] + d + slot] = (int)(pk >> 16);
    }
}

// ---------------- fused GATv2 edge kernel: one wave per node ----------------
__device__ __forceinline__ void edge_compute(
    uint32_t q, float lv, f32x2 xr2, float a04, float a14,
    float& ssum, f32x2& acc2) {
    h2 A = __builtin_bit_cast(h2, q);
    f32x2 A2 = {(float)A.x, (float)A.y};
    f32x2 t2 = A2 + xr2;
    float p = fmaf(fabsf(t2.y), a14, fabsf(t2.x) * a04);
    p = reduce16(p);
    float w = fast_exp2(p + lv);
    ssum += w;
    acc2 = __builtin_elementwise_fma((f32x2){w, w}, A2, acc2);
}

template<int OUT16>
__global__ __launch_bounds__(256) void k_gat_edge(
    const uint32_t* __restrict__ xlh, const float2* __restrict__ xrp,
    const float* __restrict__ ledl, const float* __restrict__ att,
    const float* __restrict__ bias,
    const int* __restrict__ rowptr, const int* __restrict__ csr,
    void* __restrict__ out, int N) {
    const int l = threadIdx.x & 63;
    const int n = __builtin_amdgcn_readfirstlane(blockIdx.x * 4 + (threadIdx.x >> 6));
    if (n >= N) return;
    const int h = l >> 4, j = l & 15;
    const int c0 = h * 32 + j, c1 = c0 + 16;
    const float2 xrv = xrp[(size_t)n * 64 + l];
    const f32x2 xr2 = {xrv.x, xrv.y};
    const float a04 = att[c0] * (0.4f * LOG2E), a14 = att[c1] * (0.4f * LOG2E);
    f32x2 acc2 = {0.f, 0.f};
    float ssum = 0.f;
    const int beg = rowptr[n], end = rowptr[n + 1];
    int i = beg;
    if (i + 7 < end) {
        uint32_t q0[8]; float lv0[8];
#pragma unroll
        for (int e = 0; e < 8; ++e) {
            int s = __builtin_amdgcn_readfirstlane(csr[i + e]);
            q0[e]  = xlh[(size_t)(uint32_t)s * 64 + l];
            lv0[e] = ledl[(uint32_t)s * 4 + h];
        }
        for (; i + 15 < end; i += 8) {
            uint32_t q1[8]; float lv1[8];
#pragma unroll
            for (int e = 0; e < 8; ++e) {
                int s = __builtin_amdgcn_readfirstlane(csr[i + 8 + e]);
                q1[e]  = xlh[(size_t)(uint32_t)s * 64 + l];
                lv1[e] = ledl[(uint32_t)s * 4 + h];
            }
#pragma unroll
            for (int e = 0; e < 8; ++e)
                edge_compute(q0[e], lv0[e], xr2, a04, a14, ssum, acc2);
#pragma unroll
            for (int e = 0; e < 8; ++e) { q0[e] = q1[e]; lv0[e] = lv1[e]; }
        }
#pragma unroll
        for (int e = 0; e < 8; ++e)
            edge_compute(q0[e], lv0[e], xr2, a04, a14, ssum, acc2);
        i += 8;
    }
    for (; i < end; ++i) {
        int s = __builtin_amdgcn_readfirstlane(csr[i]);
        uint32_t q = xlh[(size_t)(uint32_t)s * 64 + l];
        float lv  = ledl[(uint32_t)s * 4 + h];
        edge_compute(q, lv, xr2, a04, a14, ssum, acc2);
    }
    float inv = 1.f / ssum;
    float o0 = fmaf(acc2.x, inv, bias[c0]);
    float o1 = fmaf(acc2.y, inv, bias[c1]);
    if (OUT16) {   // layer 1: relu + fp16 pairs (feeds next GEMM via perm'd Wp2)
        o0 = fmaxf(o0, 0.f); o1 = fmaxf(o1, 0.f);
        h2 oh = {(_Float16)o0, (_Float16)o1};
        ((uint32_t*)out)[(size_t)n * 64 + l] = __builtin_bit_cast(uint32_t, oh);
    } else {       // layer 2: paired float2 for pooling
        ((float2*)out)[(size_t)n * 64 + l] = make_float2(o0, o1);
    }
}

// ---------------- pooling (slot-wise; channel perm handled in k_head) ------
__global__ __launch_bounds__(128) void k_pool(
    const float* __restrict__ h, const int* __restrict__ batch,
    float* __restrict__ pool, float* __restrict__ gcnt, int N) {
    const int NPB = 32;
    int c = threadIdx.x;
    int n0 = blockIdx.x * NPB;
    int n1 = min(n0 + NPB, N);
    float acc = 0.f;
    int curg = -1, cntl = 0;
    for (int n = n0; n < n1; ++n) {
        int g = batch[n];
        if (g != curg) {
            if (curg >= 0) {
                atomicAdd(&pool[curg * 128 + c], acc);
                if (c == 0) atomicAdd(&gcnt[curg], (float)cntl);
            }
            acc = 0.f; cntl = 0; curg = g;
        }
        acc += h[(size_t)n * 128 + c];
        cntl++;
    }
    if (curg >= 0) {
        atomicAdd(&pool[curg * 128 + c], acc);
        if (c == 0) atomicAdd(&gcnt[curg], (float)cntl);
    }
}
__global__ __launch_bounds__(64) void k_head(
    const float* __restrict__ pool, const float* __restrict__ gcnt,
    const float* __restrict__ Wlin, const float* __restrict__ blin,
    float* __restrict__ out, int G) {
    int g = blockIdx.x, l = threadIdx.x;
    float2 pv = ((const float2*)pool)[g * 64 + l];
    int c0 = (l >> 4) * 32 + (l & 15);
    float d = pv.x * Wlin[c0] + pv.y * Wlin[c0 + 16];
#pragma unroll
    for (int off = 32; off; off >>= 1) d += __shfl_xor(d, off, 64);
    if (l == 0) {
        float cnt = fmaxf(gcnt[g], 1.f);
        out[g] = d / cnt + blin[0];
    }
}

// ---------------- driver ----------------
extern "C" void kernel_launch(void* const* d_in, const int* in_sizes, int n_in,
                              void* d_out, int out_size, void* d_ws, size_t ws_size,
                              hipStream_t stream) {
    const float* x     = (const float*)d_in[0];
    const int*   ei    = (const int*)d_in[1];
    const int*   batch = (const int*)d_in[2];
    const float* Wl1   = (const float*)d_in[3];
    const float* bl1   = (const float*)d_in[4];
    const float* Wr1   = (const float*)d_in[5];
    const float* br1   = (const float*)d_in[6];
    const float* att1  = (const float*)d_in[7];
    const float* bias1 = (const float*)d_in[8];
    const float* Wl2   = (const float*)d_in[9];
    const float* bl2   = (const float*)d_in[10];
    const float* Wr2   = (const float*)d_in[11];
    const float* br2   = (const float*)d_in[12];
    const float* att2  = (const float*)d_in[13];
    const float* bias2 = (const float*)d_in[14];
    const float* Wlin  = (const float*)d_in[15];
    const float* blin  = (const float*)d_in[16];

    const int N   = in_sizes[2];
    const int E   = in_sizes[1] / 2;
    const int Fin = in_sizes[0] / N;     // 256
    const int G   = out_size;            // 64
    (void)n_in; (void)ws_size;

    char* p = (char*)d_ws;
    auto alloc = [&](size_t bytes) -> char* {
        char* r = p;
        p += (bytes + 255) & ~(size_t)255;
        return r;
    };
    uint32_t* xlh   = (uint32_t*)alloc((size_t)N * 64 * 4);  // xl fp16 pairs
    float2*   xrp   = (float2*)alloc((size_t)N * 64 * 8);    // xr fp32 pairs; aliases tmp
    uint32_t* hbh   = (uint32_t*)alloc((size_t)N * 64 * 4);  // layer1 out fp16 pairs
    float*    hbf   = (float*)alloc((size_t)N * 128 * 4);    // layer2 out fp32 pairs
    float*    ledl  = (float*)alloc((size_t)N * 4 * 4);
    float*    wt1   = (float*)alloc((size_t)Fin * 256 * 2);  // Wp1 fp16
    float*    wt2   = (float*)alloc((size_t)128 * 256 * 2);  // Wp2 fp16
    int*      rowptr= (int*)alloc((size_t)(N + 1) * 4);
    int*      csr   = (int*)alloc((size_t)(E + N) * 4);
    float*    poolg = (float*)alloc((size_t)G * 129 * 4);
    float*    pool  = poolg;
    float*    gcnt  = poolg + (size_t)G * 128;

    const int NB1 = (E + EPB - 1) / EPB;
    int*      g_hist = (int*)alloc((size_t)NB1 * NBKT * 4);
    int*      g_base = (int*)alloc((size_t)NB1 * NBKT * 4);
    int*      bstart = (int*)alloc((size_t)(NBKT + 1) * 4);
    uint32_t* tmp = (uint32_t*)xrp;   // CSR build finishes before gemm1 writes xrp
    _Float16* Wp1 = (_Float16*)wt1;
    _Float16* Wp2 = (_Float16*)wt2;

    const int wb = (N + 3) / 4;
    const int gb = (N + 63) / 64;

    // ---- CSR (bucketed radix partition + per-bucket build); hist also zeroes pool
    k_hist<<<NB1, 256, 0, stream>>>(ei + E, g_hist, E, poolg, G * 129);
    k_part_scan<<<1, 512, 0, stream>>>(g_hist, g_base, bstart, NB1, E);
    k_scatter<<<NB1, 256, 0, stream>>>(ei, g_base, tmp, E);
    k_bucket_csr<<<NBKT, 256, 0, stream>>>(tmp, bstart, rowptr, csr, N, E);

    // ---- both layers' weight packs in one launch ----
    {
        int total = (Fin / 32) * 16 * 64 + (128 / 32) * 16 * 64;
        k_wpack_all<<<(total + 255) / 256, 256, 0, stream>>>(Wl1, Wr1, Wl2, Wr2, Wp1, Wp2, Fin);
    }

    // ---- layer 1 ----
    k_gemm_mfma<256, 1><<<gb, 256, 0, stream>>>(x, Wp1, bl1, br1, att1, xlh, xrp, ledl, N);
    k_gat_edge<1><<<wb, 256, 0, stream>>>(xlh, xrp, ledl, att1, bias1, rowptr, csr, hbh, N);

    // ---- layer 2 (paired-K input; Wp2 carries matching perm) ----
    k_gemm_mfma<128, 0><<<gb, 256, 0, stream>>>(hbh, Wp2, bl2, br2, att2, xlh, xrp, ledl, N);
    k_gat_edge<0><<<wb, 256, 0, stream>>>(xlh, xrp, ledl, att2, bias2, rowptr, csr, hbf, N);

    // ---- pool + head ----
    k_pool<<<(N + 31) / 32, 128, 0, stream>>>(hbf, batch, pool, gcnt, N);
    k_head<<<G, 64, 0, stream>>>(pool, gcnt, Wlin, blin, (float*)d_out, G);
}

// Round 14
// 272.871 us; speedup vs baseline: 1.0540x; 1.0540x over previous
//
#include <hip/hip_runtime.h>
#include <hip/hip_fp16.h>
#include <math.h>
#include <stdint.h>

#define EPB 4096          // edges per block in partition kernels
#define NBKT 128          // dst>>9 buckets (98 used for N=50000)

typedef _Float16 f16x8 __attribute__((ext_vector_type(8)));
typedef float f32x4 __attribute__((ext_vector_type(4)));
typedef float f32x2 __attribute__((ext_vector_type(2)));
typedef _Float16 h2 __attribute__((ext_vector_type(2)));

#define LOG2E 1.4426950f

__device__ __forceinline__ float fast_exp2(float x) {
#if __has_builtin(__builtin_amdgcn_exp2f)
    return __builtin_amdgcn_exp2f(x);
#else
    return __expf(x * 0.69314718f);
#endif
}

// ---------- 16-lane row sum via DPP (builtin: compiler handles hazards) ----
template<int CTRL>
__device__ __forceinline__ float dpp_add(float x) {
    union { float f; int i; } u, v;
    u.f = x;
    v.i = __builtin_amdgcn_update_dpp(0, u.i, CTRL, 0xF, 0xF, true);
    return x + v.f;
}
__device__ __forceinline__ float reduce16(float x) {
    x = dpp_add<0xB1>(x);   // quad_perm xor1
    x = dpp_add<0x4E>(x);   // quad_perm xor2
    x = dpp_add<0x124>(x);  // row_ror:4
    x = dpp_add<0x128>(x);  // row_ror:8
    return x;               // all 16 lanes of the row hold the row sum
}

// ---------- pack both layers' W into MFMA B-frag order (one launch) --------
// Layer1: K=K1, no perm -> Wp1.  Layer2: K=128, paired-K perm -> Wp2.
__global__ void k_wpack_all(const float* __restrict__ Wl1, const float* __restrict__ Wr1,
                            const float* __restrict__ Wl2, const float* __restrict__ Wr2,
                            _Float16* __restrict__ Wp1, _Float16* __restrict__ Wp2,
                            int K1) {
    int t = blockIdx.x * 256 + threadIdx.x;
    int total1 = (K1 / 32) * 16 * 64;
    int total2 = (128 / 32) * 16 * 64;
    if (t < total1) {
        int l = t & 63, ct = (t >> 6) & 15, kt = t >> 10;
        int col = ct * 16 + (l & 15);
        int k0 = kt * 32 + (l >> 4) * 8;
        const float* src = (col < 128) ? (Wl1 + (size_t)col * K1)
                                       : (Wr1 + (size_t)(col - 128) * K1);
        union { _Float16 h[8]; uint4 u; } o;
#pragma unroll
        for (int e = 0; e < 8; ++e) o.h[e] = (_Float16)src[k0 + e];
        reinterpret_cast<uint4*>(Wp1)[t] = o.u;
    } else if (t < total1 + total2) {
        int t2 = t - total1;
        int l = t2 & 63, ct = (t2 >> 6) & 15, kt = t2 >> 10;
        int col = ct * 16 + (l & 15);
        int k0 = kt * 32 + (l >> 4) * 8;
        const float* src = (col < 128) ? (Wl2 + (size_t)col * 128)
                                       : (Wr2 + (size_t)(col - 128) * 128);
        union { _Float16 h[8]; uint4 u; } o;
#pragma unroll
        for (int e = 0; e < 8; ++e) {
            int k = k0 + e;
            int m = k >> 1, hh = m >> 4, j = m & 15;
            int c0 = hh * 32 + j;
            int chan = (k & 1) ? c0 + 16 : c0;
            o.h[e] = (_Float16)src[chan];
        }
        reinterpret_cast<uint4*>(Wp2)[t2] = o.u;
    }
}

// ---------- MFMA GEMM (BM=32) with fused prep epilogue ----------
// Waves 0,1 own xl cols: bias, fp16 PAIRS to xlh, ledl = 0.6*log2e*(att.xl).
// Waves 2,3 own xr cols: bias, paired float2 to xrp.
template<int K, int CVT>
__global__ __launch_bounds__(256) void k_gemm_mfma(
    const void* __restrict__ Xin, const _Float16* __restrict__ Wp,
    const float* __restrict__ bl, const float* __restrict__ br,
    const float* __restrict__ att,
    uint32_t* __restrict__ xlh, float2* __restrict__ xrp,
    float* __restrict__ ledl, int N) {
    __shared__ _Float16 xs[32 * K];
    const int t = threadIdx.x, w = t >> 6, l = t & 63;
    const int row0 = blockIdx.x * 32;
    if (CVT) {
        const float* X = (const float*)Xin;
        for (int cid = t; cid < 32 * (K / 4); cid += 256) {
            int r = cid / (K / 4), c4 = (cid % (K / 4)) * 4;
            int gr = row0 + r;
            float4 v = make_float4(0.f, 0.f, 0.f, 0.f);
            if (gr < N) v = *reinterpret_cast<const float4*>(X + (size_t)gr * K + c4);
            h2 lo = {(_Float16)v.x, (_Float16)v.y};
            h2 hi = {(_Float16)v.z, (_Float16)v.w};
            uint2 pk;
            pk.x = __builtin_bit_cast(uint32_t, lo);
            pk.y = __builtin_bit_cast(uint32_t, hi);
            int ba = (r * K * 2 + c4 * 2) ^ ((r & 7) << 4);
            *reinterpret_cast<uint2*>(reinterpret_cast<char*>(xs) + ba) = pk;
        }
    } else {
        const _Float16* X = (const _Float16*)Xin;
        for (int cid = t; cid < 32 * (K / 8); cid += 256) {
            int r = cid / (K / 8), c8 = (cid % (K / 8)) * 8;
            int gr = row0 + r;
            uint4 v = make_uint4(0u, 0u, 0u, 0u);
            if (gr < N) v = *reinterpret_cast<const uint4*>(X + (size_t)gr * K + c8);
            int ba = (r * K * 2 + c8 * 2) ^ ((r & 7) << 4);
            *reinterpret_cast<uint4*>(reinterpret_cast<char*>(xs) + ba) = v;
        }
    }
    __syncthreads();
    f32x4 acc[2][4];
#pragma unroll
    for (int m = 0; m < 2; ++m)
#pragma unroll
        for (int n = 0; n < 4; ++n) acc[m][n] = (f32x4){0.f, 0.f, 0.f, 0.f};
#pragma unroll
    for (int kt = 0; kt < K / 32; ++kt) {
        f16x8 a[2], b[4];
#pragma unroll
        for (int m = 0; m < 2; ++m) {
            int r = m * 16 + (l & 15);
            int ba = (r * K * 2 + kt * 64 + (l >> 4) * 16) ^ ((r & 7) << 4);
            a[m] = *reinterpret_cast<const f16x8*>(reinterpret_cast<const char*>(xs) + ba);
        }
#pragma unroll
        for (int n = 0; n < 4; ++n) {
            int ct = w * 4 + n;
            b[n] = *reinterpret_cast<const f16x8*>(Wp + ((size_t)(kt * 16 + ct) * 64 + l) * 8);
        }
#pragma unroll
        for (int m = 0; m < 2; ++m)
#pragma unroll
            for (int n = 0; n < 4; ++n)
                acc[m][n] = __builtin_amdgcn_mfma_f32_16x16x32_f16(a[m], b[n], acc[m][n], 0, 0, 0);
    }
    const int j = l & 15;
    if (w < 2) {
        float attv[2][2], bv[2][2];
#pragma unroll
        for (int p = 0; p < 2; ++p) {
            int c0 = (2 * w + p) * 32 + j;
            attv[p][0] = att[c0]; attv[p][1] = att[c0 + 16];
            bv[p][0] = bl[c0];    bv[p][1] = bl[c0 + 16];
        }
#pragma unroll
        for (int m = 0; m < 2; ++m)
#pragma unroll
            for (int r4 = 0; r4 < 4; ++r4) {
                int gr = row0 + m * 16 + (l >> 4) * 4 + r4;
                bool ok = gr < N;
#pragma unroll
                for (int p = 0; p < 2; ++p) {
                    int h = 2 * w + p;
                    float v0 = acc[m][2 * p][r4] + bv[p][0];
                    float v1 = acc[m][2 * p + 1][r4] + bv[p][1];
                    float part = reduce16(fmaf(attv[p][0], v0, attv[p][1] * v1));
                    if (ok) {
                        h2 hp = {(_Float16)v0, (_Float16)v1};
                        xlh[(size_t)gr * 64 + h * 16 + j] = __builtin_bit_cast(uint32_t, hp);
                        if (j == 0) ledl[gr * 4 + h] = 0.6f * LOG2E * part;
                    }
                }
            }
    } else {
        float bv[2][2];
#pragma unroll
        for (int p = 0; p < 2; ++p) {
            int c0 = (2 * (w - 2) + p) * 32 + j;
            bv[p][0] = br[c0]; bv[p][1] = br[c0 + 16];
        }
#pragma unroll
        for (int m = 0; m < 2; ++m)
#pragma unroll
            for (int r4 = 0; r4 < 4; ++r4) {
                int gr = row0 + m * 16 + (l >> 4) * 4 + r4;
                if (gr < N) {
#pragma unroll
                    for (int p = 0; p < 2; ++p) {
                        int hh = 2 * (w - 2) + p;
                        float v0 = acc[m][2 * p][r4] + bv[p][0];
                        float v1 = acc[m][2 * p + 1][r4] + bv[p][1];
                        xrp[(size_t)gr * 64 + hh * 16 + j] = make_float2(v0, v1);
                    }
                }
            }
    }
}

// ---------------- radix partition by dst>>9 (scan-based, no global RMW) ----
// Also zeroes the pool buffer (folded launch).
__global__ __launch_bounds__(256) void k_hist(const int* __restrict__ dstArr,
                                              int* __restrict__ g_hist, int E,
                                              float* __restrict__ zbuf, int zn) {
    __shared__ int h[NBKT];
    int t = threadIdx.x;
    int zi = blockIdx.x * 256 + t;
    if (zi < zn) zbuf[zi] = 0.f;
    if (t < NBKT) h[t] = 0;
    __syncthreads();
    int s0 = blockIdx.x * EPB, s1 = min(E, s0 + EPB);
    for (int i = s0 + t; i < s1; i += 256) atomicAdd(&h[dstArr[i] >> 9], 1);
    __syncthreads();
    if (t < NBKT) g_hist[blockIdx.x * NBKT + t] = h[t];
}
__global__ __launch_bounds__(512) void k_part_scan(const int* __restrict__ g_hist,
                                                   int* __restrict__ g_base,
                                                   int* __restrict__ bstart_out,
                                                   int NB1, int E) {
    __shared__ int csum[4][NBKT];
    __shared__ int btot[NBKT];
    __shared__ int bstart[NBKT];
    int tid = threadIdx.x, c = tid >> 7, b = tid & (NBKT - 1);
    int chunk = (NB1 + 3) >> 2;
    int i0 = c * chunk, i1 = min(NB1, i0 + chunk);
    int run = 0;
    for (int i = i0; i < i1; ++i) run += g_hist[i * NBKT + b];
    csum[c][b] = run;
    __syncthreads();
    int mytot = 0;
    if (c == 0) {
        mytot = csum[0][b] + csum[1][b] + csum[2][b] + csum[3][b];
        btot[b] = mytot;
    }
    __syncthreads();
    for (int off = 1; off < NBKT; off <<= 1) {
        int add = 0;
        if (c == 0 && b >= off) add = btot[b - off];
        __syncthreads();
        if (c == 0) btot[b] += add;
        __syncthreads();
    }
    if (c == 0) { bstart[b] = btot[b] - mytot; bstart_out[b] = bstart[b]; }
    if (tid == 0) bstart_out[NBKT] = E;
    __syncthreads();
    int base = bstart[b];
    for (int cc = 0; cc < c; ++cc) base += csum[cc][b];
    run = base;
    for (int i = i0; i < i1; ++i) {
        g_base[i * NBKT + b] = run;
        run += g_hist[i * NBKT + b];
    }
}
__global__ __launch_bounds__(256) void k_scatter(const int* __restrict__ ei,
                                                 const int* __restrict__ g_base,
                                                 uint32_t* __restrict__ tmp, int E) {
    __shared__ int off[NBKT];
    int t = threadIdx.x;
    if (t < NBKT) off[t] = g_base[blockIdx.x * NBKT + t];
    __syncthreads();
    int s0 = blockIdx.x * EPB, s1 = min(E, s0 + EPB);
    for (int i = s0 + t; i < s1; i += 256) {
        int s = ei[i], d = ei[E + i];
        int pos = atomicAdd(&off[d >> 9], 1);
        tmp[pos] = ((uint32_t)s << 16) | (uint32_t)d;
    }
}
// One block per 512-node bucket: LDS hist+scan -> rowptr, self-loops, and
// ordered edge placement, all within a ~67KB contiguous csr window.
__global__ __launch_bounds__(256) void k_bucket_csr(
    const uint32_t* __restrict__ tmp, const int* __restrict__ bstart,
    int* __restrict__ rowptr, int* __restrict__ csr, int N, int E) {
    __shared__ int cnt[512];
    __shared__ int fil[512];
    int b = blockIdx.x, t = threadIdx.x;
    int s0 = bstart[b], s1 = bstart[b + 1];
    cnt[t] = 0; cnt[t + 256] = 0;
    __syncthreads();
    for (int i = s0 + t; i < s1; i += 256)
        atomicAdd(&cnt[tmp[i] & 511], 1);
    __syncthreads();
    int c0 = cnt[t], c1 = cnt[t + 256];
    for (int off = 1; off < 512; off <<= 1) {
        int v0 = (t >= off) ? cnt[t - off] : 0;
        int v1 = (t + 256 >= off) ? cnt[t + 256 - off] : 0;
        __syncthreads();
        cnt[t] += v0; cnt[t + 256] += v1;
        __syncthreads();
    }
    int e0 = cnt[t] - c0, e1 = cnt[t + 256] - c1;   // exclusive
    __syncthreads();
    cnt[t] = e0; cnt[t + 256] = e1;
    fil[t] = 1; fil[t + 256] = 1;                   // slot 0 = self-loop
    __syncthreads();
    int n0 = b * 512;
#pragma unroll
    for (int k = 0; k < 2; ++k) {
        int ld = t + k * 256, n = n0 + ld;
        if (n < N) {
            int rp = s0 + cnt[ld] + n;              // edgesBefore + selfLoopsBefore
            rowptr[n] = rp;
            csr[rp] = n;
        }
    }
    if (b == 0 && t == 0) rowptr[N] = E + N;
    for (int i = s0 + t; i < s1; i += 256) {
        uint32_t pk = tmp[i];
        int d = (int)(pk & 0xFFFFu), ld = d & 511;
        int slot = atomicAdd(&fil[ld], 1);
        csr[s0 + cnt[ld] + d + slot] = (int)(pk >> 16);
    }
}

// ---------------- fused GATv2 edge kernel: one wave per node ----------------
// w_e = exp2( reduce16(0.4*L*att.|xl_s+xr_d|) + ledl_s ).  Source indices are
// forced into SGPRs (readfirstlane) so gathers use saddr + const lane voffset.
template<int OUT16>
__global__ __launch_bounds__(256) void k_gat_edge(
    const uint32_t* __restrict__ xlh, const float2* __restrict__ xrp,
    const float* __restrict__ ledl, const float* __restrict__ att,
    const float* __restrict__ bias,
    const int* __restrict__ rowptr, const int* __restrict__ csr,
    void* __restrict__ out, int N) {
    const int l = threadIdx.x & 63;
    const int n = __builtin_amdgcn_readfirstlane(blockIdx.x * 4 + (threadIdx.x >> 6));
    if (n >= N) return;
    const int h = l >> 4, j = l & 15;
    const int c0 = h * 32 + j, c1 = c0 + 16;
    const float2 xrv = xrp[(size_t)n * 64 + l];
    const f32x2 xr2 = {xrv.x, xrv.y};
    const float a04 = att[c0] * (0.4f * LOG2E), a14 = att[c1] * (0.4f * LOG2E);
    f32x2 acc2 = {0.f, 0.f};
    float ssum = 0.f;
    const int beg = rowptr[n], end = rowptr[n + 1];
    int i = beg;
    for (; i + 7 < end; i += 8) {
        int sr[8];
#pragma unroll
        for (int e = 0; e < 8; ++e) sr[e] = __builtin_amdgcn_readfirstlane(csr[i + e]);
        uint32_t q[8]; float lv[8];
#pragma unroll
        for (int e = 0; e < 8; ++e) {
            q[e]  = xlh[(size_t)(uint32_t)sr[e] * 64 + l];
            lv[e] = ledl[(uint32_t)sr[e] * 4 + h];
        }
#pragma unroll
        for (int e = 0; e < 8; ++e) {
            h2 A = __builtin_bit_cast(h2, q[e]);
            f32x2 A2 = {(float)A.x, (float)A.y};
            f32x2 t2 = A2 + xr2;
            float p = fmaf(fabsf(t2.y), a14, fabsf(t2.x) * a04);
            p = reduce16(p);
            float w = fast_exp2(p + lv[e]);
            ssum += w;
            acc2 = __builtin_elementwise_fma((f32x2){w, w}, A2, acc2);
        }
    }
    for (; i < end; ++i) {
        int s = __builtin_amdgcn_readfirstlane(csr[i]);
        uint32_t q = xlh[(size_t)(uint32_t)s * 64 + l];
        float lv  = ledl[(uint32_t)s * 4 + h];
        h2 A = __builtin_bit_cast(h2, q);
        f32x2 A2 = {(float)A.x, (float)A.y};
        f32x2 t2 = A2 + xr2;
        float p = fmaf(fabsf(t2.y), a14, fabsf(t2.x) * a04);
        p = reduce16(p);
        float w = fast_exp2(p + lv);
        ssum += w;
        acc2 = __builtin_elementwise_fma((f32x2){w, w}, A2, acc2);
    }
    float inv = 1.f / ssum;
    float o0 = fmaf(acc2.x, inv, bias[c0]);
    float o1 = fmaf(acc2.y, inv, bias[c1]);
    if (OUT16) {   // layer 1: relu + fp16 pairs (feeds next GEMM via perm'd Wp2)
        o0 = fmaxf(o0, 0.f); o1 = fmaxf(o1, 0.f);
        h2 oh = {(_Float16)o0, (_Float16)o1};
        ((uint32_t*)out)[(size_t)n * 64 + l] = __builtin_bit_cast(uint32_t, oh);
    } else {       // layer 2: paired float2 for pooling
        ((float2*)out)[(size_t)n * 64 + l] = make_float2(o0, o1);
    }
}

// ---------------- pooling (slot-wise; channel perm handled in k_head) ------
__global__ __launch_bounds__(128) void k_pool(
    const float* __restrict__ h, const int* __restrict__ batch,
    float* __restrict__ pool, float* __restrict__ gcnt, int N) {
    const int NPB = 32;
    int c = threadIdx.x;
    int n0 = blockIdx.x * NPB;
    int n1 = min(n0 + NPB, N);
    float acc = 0.f;
    int curg = -1, cntl = 0;
    for (int n = n0; n < n1; ++n) {
        int g = batch[n];
        if (g != curg) {
            if (curg >= 0) {
                atomicAdd(&pool[curg * 128 + c], acc);
                if (c == 0) atomicAdd(&gcnt[curg], (float)cntl);
            }
            acc = 0.f; cntl = 0; curg = g;
        }
        acc += h[(size_t)n * 128 + c];
        cntl++;
    }
    if (curg >= 0) {
        atomicAdd(&pool[curg * 128 + c], acc);
        if (c == 0) atomicAdd(&gcnt[curg], (float)cntl);
    }
}
__global__ __launch_bounds__(64) void k_head(
    const float* __restrict__ pool, const float* __restrict__ gcnt,
    const float* __restrict__ Wlin, const float* __restrict__ blin,
    float* __restrict__ out, int G) {
    int g = blockIdx.x, l = threadIdx.x;
    float2 pv = ((const float2*)pool)[g * 64 + l];
    int c0 = (l >> 4) * 32 + (l & 15);
    float d = pv.x * Wlin[c0] + pv.y * Wlin[c0 + 16];
#pragma unroll
    for (int off = 32; off; off >>= 1) d += __shfl_xor(d, off, 64);
    if (l == 0) {
        float cnt = fmaxf(gcnt[g], 1.f);
        out[g] = d / cnt + blin[0];
    }
}

// ---------------- driver ----------------
extern "C" void kernel_launch(void* const* d_in, const int* in_sizes, int n_in,
                              void* d_out, int out_size, void* d_ws, size_t ws_size,
                              hipStream_t stream) {
    const float* x     = (const float*)d_in[0];
    const int*   ei    = (const int*)d_in[1];
    const int*   batch = (const int*)d_in[2];
    const float* Wl1   = (const float*)d_in[3];
    const float* bl1   = (const float*)d_in[4];
    const float* Wr1   = (const float*)d_in[5];
    const float* br1   = (const float*)d_in[6];
    const float* att1  = (const float*)d_in[7];
    const float* bias1 = (const float*)d_in[8];
    const float* Wl2   = (const float*)d_in[9];
    const float* bl2   = (const float*)d_in[10];
    const float* Wr2   = (const float*)d_in[11];
    const float* br2   = (const float*)d_in[12];
    const float* att2  = (const float*)d_in[13];
    const float* bias2 = (const float*)d_in[14];
    const float* Wlin  = (const float*)d_in[15];
    const float* blin  = (const float*)d_in[16];

    const int N   = in_sizes[2];
    const int E   = in_sizes[1] / 2;
    const int Fin = in_sizes[0] / N;     // 256
    const int G   = out_size;            // 64
    (void)n_in; (void)ws_size;

    char* p = (char*)d_ws;
    auto alloc = [&](size_t bytes) -> char* {
        char* r = p;
        p += (bytes + 255) & ~(size_t)255;
        return r;
    };
    uint32_t* xlh   = (uint32_t*)alloc((size_t)N * 64 * 4);  // xl fp16 pairs
    float2*   xrp   = (float2*)alloc((size_t)N * 64 * 8);    // xr fp32 pairs; aliases tmp
    uint32_t* hbh   = (uint32_t*)alloc((size_t)N * 64 * 4);  // layer1 out fp16 pairs
    float*    hbf   = (float*)alloc((size_t)N * 128 * 4);    // layer2 out fp32 pairs
    float*    ledl  = (float*)alloc((size_t)N * 4 * 4);
    float*    wt1   = (float*)alloc((size_t)Fin * 256 * 2);  // Wp1 fp16
    float*    wt2   = (float*)alloc((size_t)128 * 256 * 2);  // Wp2 fp16
    int*      rowptr= (int*)alloc((size_t)(N + 1) * 4);
    int*      csr   = (int*)alloc((size_t)(E + N) * 4);
    float*    poolg = (float*)alloc((size_t)G * 129 * 4);
    float*    pool  = poolg;
    float*    gcnt  = poolg + (size_t)G * 128;

    const int NB1 = (E + EPB - 1) / EPB;
    int*      g_hist = (int*)alloc((size_t)NB1 * NBKT * 4);
    int*      g_base = (int*)alloc((size_t)NB1 * NBKT * 4);
    int*      bstart = (int*)alloc((size_t)(NBKT + 1) * 4);
    uint32_t* tmp = (uint32_t*)xrp;   // CSR build finishes before gemm1 writes xrp
    _Float16* Wp1 = (_Float16*)wt1;
    _Float16* Wp2 = (_Float16*)wt2;

    const int wb = (N + 3) / 4;
    const int gb = (N + 31) / 32;

    // ---- CSR (bucketed radix partition + per-bucket build); hist also zeroes pool
    k_hist<<<NB1, 256, 0, stream>>>(ei + E, g_hist, E, poolg, G * 129);
    k_part_scan<<<1, 512, 0, stream>>>(g_hist, g_base, bstart, NB1, E);
    k_scatter<<<NB1, 256, 0, stream>>>(ei, g_base, tmp, E);
    k_bucket_csr<<<NBKT, 256, 0, stream>>>(tmp, bstart, rowptr, csr, N, E);

    // ---- both layers' weight packs in one launch ----
    {
        int total = (Fin / 32) * 16 * 64 + (128 / 32) * 16 * 64;
        k_wpack_all<<<(total + 255) / 256, 256, 0, stream>>>(Wl1, Wr1, Wl2, Wr2, Wp1, Wp2, Fin);
    }

    // ---- layer 1 ----
    k_gemm_mfma<256, 1><<<gb, 256, 0, stream>>>(x, Wp1, bl1, br1, att1, xlh, xrp, ledl, N);
    k_gat_edge<1><<<wb, 256, 0, stream>>>(xlh, xrp, ledl, att1, bias1, rowptr, csr, hbh, N);

    // ---- layer 2 (paired-K input; Wp2 carries matching perm) ----
    k_gemm_mfma<128, 0><<<gb, 256, 0, stream>>>(hbh, Wp2, bl2, br2, att2, xlh, xrp, ledl, N);
    k_gat_edge<0><<<wb, 256, 0, stream>>>(xlh, xrp, ledl, att2, bias2, rowptr, csr, hbf, N);

    // ---- pool + head ----
    k_pool<<<(N + 31) / 32, 128, 0, stream>>>(hbf, batch, pool, gcnt, N);
    k_head<<<G, 64, 0, stream>>>(pool, gcnt, Wlin, blin, (float*)d_out, G);
}